// Round 6
// baseline (340.992 us; speedup 1.0000x reference)
//
#include <hip/hip_runtime.h>
#include <math.h>

// Pool2d: 3x3 max pool, stride 2, pad 1 (fill 0.0), dilation 1.
// X: (32,192,224,224) f32 NCHW -> Y: (32,192,112,112) f32.
// Compulsory traffic: 1.233 GB read + 0.308 GB write (~245 us @ 6.3 TB/s).
//
// R6: LDS-staged stencil -- tests the load-density hypothesis.
//  - one block per (channel, quarter): stage 57 input rows (51 KB LDS,
//    3 blocks/CU) with 100%-dense float4 global loads (16 B/lane,
//    consecutive lanes consecutive addresses),
//  - one barrier, then 784 1x4-output quads computed from LDS,
//    dense nontemporal float4 stores.
//  - rows deduplicated by LDS (not register tiling): reads ~compulsory
//    (+1.3% quarter-overlap rows).

namespace {
constexpr int H = 224;
constexpr int W = 224;
constexpr int HO = 112;
constexpr int WO = 112;
constexpr int NC = 32 * 192;          // 6144 channels
constexpr int OROWS = 28;             // output rows per block (quarter)
constexpr int IROWS = 57;             // input rows staged (2*28+1)
constexpr int F4PR = W / 4;           // 56 float4 per input row
constexpr int NF4 = IROWS * F4PR;     // 3192 float4 loads per block
constexpr int LDSF = IROWS * W;       // 12768 floats = 51072 B
constexpr int NQUAD = OROWS * (WO / 4);  // 784 output quads per block

typedef float v4f __attribute__((ext_vector_type(4)));
}

__global__ __launch_bounds__(256) void pool3x3s2_lds(
    const float* __restrict__ X, float* __restrict__ Y) {
  __shared__ float lds[LDSF];
  const int b   = blockIdx.x;
  const int Q   = b & 3;               // quarter 0..3
  const int nc  = b >> 2;
  const int tid = threadIdx.x;

  const float* __restrict__ img = X + (size_t)nc * (H * W);
  const int ibase = 56 * Q - 1;        // LDS row r holds input row ibase+r
                                       // (r=0 at Q=0 is the 0.0 pad row;
                                       //  ibase+56 = 56Q+55 <= 223 always)

  // ---- load phase: dense float4, global and LDS both linear ----
  for (int f = tid; f < NF4; f += 256) {
    const int r = f / F4PR;            // magic-div
    const int c = f - r * F4PR;
    const int iy = ibase + r;
    v4f v;
    if (iy >= 0) {
      v = *reinterpret_cast<const v4f*>(img + iy * W + 4 * c);
    } else {
      v = 0.0f;                        // pad row, fill value 0.0
    }
    *reinterpret_cast<v4f*>(&lds[4 * f]) = v;   // 4f == r*224 + 4c
  }
  __syncthreads();

  // ---- compute phase: 1x4 output quads from LDS ----
  float* __restrict__ outq = Y + (size_t)nc * (HO * WO) + Q * OROWS * WO;
  for (int hq = tid; hq < NQUAD; hq += 256) {
    const int oy = hq / 28;            // local output row 0..27
    const int q  = hq - oy * 28;       // quad 0..27 (cols 4q..4q+3)

    float m0 = -INFINITY, m1 = -INFINITY, m2 = -INFINITY, m3 = -INFINITY;
#pragma unroll
    for (int d = 0; d < 3; ++d) {
      const float* __restrict__ lr = &lds[(2 * oy + d) * W + 8 * q];
      const float a = (q > 0) ? lr[-1] : 0.0f;   // left pad = 0.0
      const v4f v0 = *reinterpret_cast<const v4f*>(lr);
      const v4f v1 = *reinterpret_cast<const v4f*>(lr + 4);
      m0 = fmaxf(m0, fmaxf(fmaxf(a,    v0.x), v0.y));
      m1 = fmaxf(m1, fmaxf(fmaxf(v0.y, v0.z), v0.w));
      m2 = fmaxf(m2, fmaxf(fmaxf(v0.w, v1.x), v1.y));
      m3 = fmaxf(m3, fmaxf(fmaxf(v1.y, v1.z), v1.w));
    }
    v4f o;
    o.x = m0; o.y = m1; o.z = m2; o.w = m3;
    __builtin_nontemporal_store(
        o, reinterpret_cast<v4f*>(outq + oy * WO + 4 * q));
  }
}

extern "C" void kernel_launch(void* const* d_in, const int* in_sizes, int n_in,
                              void* d_out, int out_size, void* d_ws, size_t ws_size,
                              hipStream_t stream) {
  const float* X = (const float*)d_in[0];
  float* Y = (float*)d_out;
  pool3x3s2_lds<<<NC * 4, 256, 0, stream>>>(X, Y);
}

// Round 7
// 276.339 us; speedup vs baseline: 1.2340x; 1.2340x over previous
//
#include <hip/hip_runtime.h>
#include <math.h>

// Pool2d: 3x3 max pool, stride 2, pad 1 (fill 0.0), dilation 1.
// X: (32,192,224,224) f32 NCHW -> Y: (32,192,112,112) f32.
// Compulsory traffic: 1.233 GB read + 0.308 GB write.
//
// R7: 4x4 output tile per thread (rows 4s..4s+3 x cols 4q..4q+3).
//  - 9 input rows per 16 outputs (R5: 10 per 16) -> fewer redundant
//    L1 re-reads, 1.41 load-instrs/output vs 1.875.
//  - same proven access pattern as R5: 2 aligned float4 + 1 scalar left
//    tap per row, 16 B/lane at 32-B stride; exact-cover grid; NT stores.
//  - rolling accumulation (each row's h feeds <=2 outputs) keeps live
//    state small; loads still hoistable by the compiler for MLP.

namespace {
constexpr int H = 224;
constexpr int W = 224;
constexpr int HO = 112;
constexpr int WO = 112;
constexpr int QPR = WO / 4;              // 28 col-quads per output row
constexpr int SPC = HO / 4;              // 28 4-row tiles per channel
constexpr int NC = 32 * 192;
constexpr int TOTAL = NC * SPC * QPR;    // 4,816,896 threads = 18816 blocks

typedef float v4f __attribute__((ext_vector_type(4)));
}

__global__ __launch_bounds__(256) void pool3x3s2_tile4x4(
    const float* __restrict__ X, float* __restrict__ Y) {
  const int idx = blockIdx.x * blockDim.x + threadIdx.x;  // exact cover
  const int q  = idx % QPR;              // output cols 4q..4q+3
  const int t  = idx / QPR;
  const int s  = t % SPC;                // output rows 4s..4s+3
  const int nc = t / SPC;

  const float* __restrict__ img = X + (size_t)nc * (H * W);
  const int ixs = 8 * q;                 // window x = [ixs-1, ixs+7]
  const int iy0 = 8 * s - 1;             // input rows iy0..iy0+8; only
                                         // iy=-1 (s==0) is OOB; max 223.

  float o[4][4];                         // 4 output rows x 4 cols
#pragma unroll
  for (int k = 0; k < 4; ++k)
#pragma unroll
    for (int j = 0; j < 4; ++j) o[k][j] = -INFINITY;

#pragma unroll
  for (int r = 0; r < 9; ++r) {
    const int iy = iy0 + r;
    float a, b0, b1, b2, b3, b4, b5, b6, b7;
    if (iy >= 0) {
      const float* __restrict__ row = img + iy * W + ixs;
      a = (ixs > 0) ? row[-1] : 0.0f;    // left pad = fill 0.0
      const v4f v0 = *reinterpret_cast<const v4f*>(row);
      const v4f v1 = *reinterpret_cast<const v4f*>(row + 4);
      b0 = v0.x; b1 = v0.y; b2 = v0.z; b3 = v0.w;
      b4 = v1.x; b5 = v1.y; b6 = v1.z; b7 = v1.w;
    } else {                             // padded row -> fill 0.0
      a = b0 = b1 = b2 = b3 = b4 = b5 = b6 = b7 = 0.0f;
    }
    float h0 = fmaxf(fmaxf(a,  b0), b1); // col j taps x = 2j-1..2j+1
    float h1 = fmaxf(fmaxf(b1, b2), b3);
    float h2 = fmaxf(fmaxf(b3, b4), b5);
    float h3 = fmaxf(fmaxf(b5, b6), b7);
    // Output row k (local) taps input rows 2k..2k+2 (local r).
#pragma unroll
    for (int k = 0; k < 4; ++k) {
      if (r >= 2 * k && r <= 2 * k + 2) {
        o[k][0] = fmaxf(o[k][0], h0);
        o[k][1] = fmaxf(o[k][1], h1);
        o[k][2] = fmaxf(o[k][2], h2);
        o[k][3] = fmaxf(o[k][3], h3);
      }
    }
  }

  float* __restrict__ out = Y + ((size_t)nc * HO + 4 * s) * WO + 4 * q;
#pragma unroll
  for (int k = 0; k < 4; ++k) {
    v4f v;
    v.x = o[k][0]; v.y = o[k][1]; v.z = o[k][2]; v.w = o[k][3];
    __builtin_nontemporal_store(v, reinterpret_cast<v4f*>(out + k * WO));
  }
}

extern "C" void kernel_launch(void* const* d_in, const int* in_sizes, int n_in,
                              void* d_out, int out_size, void* d_ws, size_t ws_size,
                              hipStream_t stream) {
  const float* X = (const float*)d_in[0];
  float* Y = (float*)d_out;
  pool3x3s2_tile4x4<<<TOTAL / 256, 256, 0, stream>>>(X, Y);
}